// Round 10
// baseline (264.346 us; speedup 1.0000x reference)
//
#include <hip/hip_runtime.h>
#include <math.h>

#define CHUNK 8192
#define BSH 8            // bucket shift: 256 nodes per bucket
#define BNODES 256
#define RAWCAP 9216      // LDS edge capacity per bucket (avg 8192, sigma ~90 -> +11 sigma)
#define MAXCELL 512      // max chunks supported (E <= 4.19M); also requires nb <= 511

// Workspace layout (4-byte units, NO aliasing; ~33 MB total):
//   dinv  : N            rsqrt(1+deg)
//   ptrS  : N+1          CSR row starts (ptrS[N] = E)
//   base  : nb+1         exclusive bucket bases (base[nb] = E)
//   off   : (nb+1)*NBLK  ushort per-(bucket,chunk) exclusive offsets
//   csr   : E            source nodes grouped by destination
//   temp  : E            binned packed edges
//   h0u   : 8N u32       packed fp16 feature table, layer-1 input (dinv-premultiplied)
//   h1u   : 8N u32       packed fp16 feature table, layer-2 input
//   g     : 16G          pooled graph accumulator

union H2 { unsigned int u; _Float16 h[2]; };

// Phase 1: bin this block's 8192-edge chunk by destination bucket.
// 1024 threads, wave-shuffle scan (2 barriers), no global atomics.
__global__ __launch_bounds__(1024) void k_bin(
                      const int* __restrict__ row, const int* __restrict__ col,
                      int* __restrict__ temp, unsigned short* __restrict__ off,
                      int E, int NBLK, int nb) {
    __shared__ int cnt[512];
    __shared__ int cur[512];
    __shared__ int wsum[8];
    __shared__ int stage[CHUNK];
    int blk = blockIdx.x;
    int start = blk * CHUNK;
    int cs = E - start; if (cs > CHUNK) cs = CHUNK;
    int t = threadIdx.x;     // 1024 threads = 16 waves
    int wid = t >> 6, lane = t & 63;
    if (t < 512) cnt[t] = 0;
    __syncthreads();
    for (int i = t; i < cs; i += 1024) atomicAdd(&cnt[col[start + i] >> BSH], 1);
    __syncthreads();
    if (t < 512) {           // waves 0..7 scan the 512 bucket counters
        int c = cnt[t];
        int incl = c;
        for (int o = 1; o < 64; o <<= 1) {
            int u = __shfl_up(incl, o, 64);
            if (lane >= o) incl += u;
        }
        if (lane == 63) wsum[wid] = incl;
        cnt[t] = incl - c;   // within-wave exclusive
    }
    __syncthreads();
    if (t < 512) {
        int wb = 0;
        for (int i = 0; i < wid; ++i) wb += wsum[i];
        int excl = cnt[t] + wb;
        if (t < nb) off[t * NBLK + blk] = (unsigned short)excl;
        if (t == 0) off[nb * NBLK + blk] = (unsigned short)cs;
        cur[t] = excl;
    }
    __syncthreads();
    for (int i = t; i < cs; i += 1024) {
        int cc = col[start + i];         // L2-hot re-read (same 32KB window)
        int rr = row[start + i];
        int p = atomicAdd(&cur[cc >> BSH], 1);
        stage[p] = (rr << BSH) | (cc & (BNODES - 1));
    }
    __syncthreads();
    for (int i = t; i < cs; i += 1024) temp[start + i] = stage[i];
}

// Bucket totals from off-table row-sums (tot[b] = rs[b+1]-rs[b]), exclusive
// scan -> base; sentinels; zero g. One small block. Requires nb <= 511.
__global__ __launch_bounds__(512) void k_base(
                       const unsigned short* __restrict__ off, int* __restrict__ base,
                       int* __restrict__ ptrS, float* __restrict__ g,
                       int E, int nb, int NBLK, int N, int G16) {
    __shared__ int rs[512];
    __shared__ int wsum[8];
    int t = threadIdx.x;
    int wid = t >> 6, lane = t & 63;
    int rsv = 0;
    if (t <= nb) {
        const unsigned short* orow = off + (size_t)t * NBLK;
        for (int ch = 0; ch < NBLK; ++ch) rsv += orow[ch];
    }
    rs[t] = rsv;
    __syncthreads();
    int tb = (t < nb) ? rs[t + 1] - rs[t] : 0;
    int incl = tb;
    for (int o = 1; o < 64; o <<= 1) {
        int u = __shfl_up(incl, o, 64);
        if (lane >= o) incl += u;
    }
    if (lane == 63) wsum[wid] = incl;
    __syncthreads();
    int wb = 0;
    for (int i = 0; i < wid; ++i) wb += wsum[i];
    if (t < nb) base[t] = incl - tb + wb;
    if (t == 0) { base[nb] = E; ptrS[N] = E; }
    for (int i = t; i < G16; i += 512) g[i] = 0.0f;
}

// Phase 2: one block per 256-node bucket, 1024 threads. Builds ptrS/dinv/csr
// (LDS-staged, coalesced writeback) AND computes the bucket's h0u rows
// (fused xw1: h0u = fp16(dinv * x@W1), packed pairs). h0u must NOT alias temp.
__global__ __launch_bounds__(1024) void k_build(
                        const int* __restrict__ temp, const unsigned short* __restrict__ off,
                        const int* __restrict__ base, int* __restrict__ ptrS,
                        float* __restrict__ dinv, int* __restrict__ csr,
                        const float* __restrict__ x, const float* __restrict__ W1,
                        unsigned int* __restrict__ h0u, int NBLK, int N) {
    __shared__ int cnt[BNODES];
    __shared__ int cur[BNODES];
    __shared__ int cellstart[MAXCELL];
    __shared__ int soff[MAXCELL];
    __shared__ int wsum[16];
    __shared__ float sdinv[BNODES];
    __shared__ int raw[RAWCAP];
    __shared__ int stage[RAWCAP];
    int b = blockIdx.x;
    int t = threadIdx.x;     // 1024 threads = 16 waves
    int wid = t >> 6, lane = t & 63;
    if (t < BNODES) cnt[t] = 0;
    int len0 = 0;
    if (t < MAXCELL) {
        int s0v = 0;
        if (t < NBLK) {
            s0v = (int)off[b * NBLK + t];
            len0 = (int)off[(b + 1) * NBLK + t] - s0v;
        }
        soff[t] = s0v;
        int v = len0;
        for (int o = 1; o < 64; o <<= 1) {
            int u = __shfl_up(v, o, 64);
            if (lane >= o) v += u;
        }
        if (lane == 63) wsum[wid] = v;
        cellstart[t] = v - len0;
    }
    __syncthreads();
    if (t < MAXCELL) {
        int wb = 0;
        for (int i = 0; i < wid; ++i) wb += wsum[i];
        cellstart[t] += wb;
    }
    __syncthreads();
    int bb = base[b];
    int total = base[b + 1] - bb;
    int grp = t >> 4, gl = t & 15;     // 64 groups of 16 lanes
    for (int cell = grp; cell < NBLK; cell += 64) {
        int s0 = soff[cell];
        int rb = cellstart[cell];
        int len = ((cell + 1 < NBLK) ? cellstart[cell + 1] : total) - rb;
        const int* src = temp + cell * CHUNK + s0;
        for (int j = gl; j < len; j += 16) {
            int e = src[j];
            atomicAdd(&cnt[e & (BNODES - 1)], 1);
            int idx = rb + j;
            if (idx < RAWCAP) raw[idx] = e;
        }
    }
    __syncthreads();
    int c = 0, sincl = 0;
    if (t < BNODES) {
        c = cnt[t];
        sincl = c;
        for (int o = 1; o < 64; o <<= 1) {
            int u = __shfl_up(sincl, o, 64);
            if (lane >= o) sincl += u;
        }
        if (lane == 63) wsum[wid] = sincl;
    }
    __syncthreads();
    if (t < BNODES) {
        int wb2 = 0;
        for (int i = 0; i < wid; ++i) wb2 += wsum[i];
        int lstart = sincl - c + wb2;
        int node = (b << BSH) + t;
        float dv = rsqrtf(1.0f + (float)c);
        sdinv[t] = dv;
        if (node < N) {
            ptrS[node] = bb + lstart;
            dinv[node] = dv;
        }
        cur[t] = lstart;
    }
    __syncthreads();
    int cap = total > RAWCAP ? RAWCAP : total;
    for (int i = t; i < cap; i += 1024) {
        int e = raw[i];
        int p = atomicAdd(&cur[e & (BNODES - 1)], 1);
        int r = e >> BSH;
        if (p < RAWCAP) stage[p] = r;
        else            csr[bb + p] = r;   // statistically unreachable
    }
    if (total > RAWCAP) {                  // statistically unreachable spill
        for (int cell = grp; cell < NBLK; cell += 64) {
            int s0 = soff[cell];
            int rb = cellstart[cell];
            int len = ((cell + 1 < NBLK) ? cellstart[cell + 1] : total) - rb;
            const int* src = temp + cell * CHUNK + s0;
            for (int j = gl; j < len; j += 16) {
                if (rb + j >= RAWCAP) {
                    int e = src[j];
                    int p = atomicAdd(&cur[e & (BNODES - 1)], 1);
                    int r = e >> BSH;
                    if (p < RAWCAP) stage[p] = r;
                    else            csr[bb + p] = r;
                }
            }
        }
    }
    __syncthreads();
    for (int i = t; i < cap; i += 1024) csr[bb + i] = stage[i];
    // Fused xw1 epilogue for this bucket's 256 nodes (2048 packed u32 writes).
    for (int i = t; i < BNODES * 8; i += 1024) {
        int vl = i >> 3, k2 = i & 7, k = k2 * 2;
        int v = (b << BSH) + vl;
        if (v < N) {
            float x0 = x[v * 3 + 0], x1 = x[v * 3 + 1], x2 = x[v * 3 + 2];
            float d = sdinv[vl];
            H2 p;
            p.h[0] = (_Float16)(d * (x0 * W1[k]     + x1 * W1[16 + k]     + x2 * W1[32 + k]));
            p.h[1] = (_Float16)(d * (x0 * W1[k + 1] + x1 * W1[16 + k + 1] + x2 * W1[32 + k + 1]));
            h0u[v * 8 + k2] = p.u;
        }
    }
}

// Layer-1 gather: 8 lanes/node, packed-u32 rows. Per 8-edge window: ONE coalesced
// csr load + __shfl broadcast + 8 u32 table loads servicing 8 nodes/wave.
// f32 accumulation; relu + W2 via 8-lane shfl; packed fp16 store.
__global__ void k_gather1(const int* __restrict__ ptrS, const int* __restrict__ csr,
                          const float* __restrict__ dinv, const unsigned int* __restrict__ h0u,
                          const float* __restrict__ W2, const float* __restrict__ b1,
                          unsigned int* __restrict__ h1u, int N) {
    __shared__ float sW[256];
    sW[threadIdx.x] = W2[threadIdx.x];
    __syncthreads();
    int t = blockIdx.x * blockDim.x + threadIdx.x;
    int v = t >> 3, gl = t & 7, k = gl * 2;
    if (v >= N) return;
    int s = ptrS[v], e = ptrS[v + 1];
    float al0 = 0.0f, ah0 = 0.0f, al1 = 0.0f, ah1 = 0.0f;
    int i = s;
    for (; i + 7 < e; i += 8) {
        int myr = __builtin_nontemporal_load(csr + i + gl);
#pragma unroll
        for (int q = 0; q < 8; ++q) {
            int r = __shfl(myr, q, 8);
            H2 p; p.u = h0u[r * 8 + gl];
            if (q & 1) { al1 += (float)p.h[0]; ah1 += (float)p.h[1]; }
            else       { al0 += (float)p.h[0]; ah0 += (float)p.h[1]; }
        }
    }
    if (i < e) {
        int rem = e - i;
        int myr = (gl < rem) ? __builtin_nontemporal_load(csr + i + gl) : 0;
        for (int q = 0; q < rem; ++q) {
            int r = __shfl(myr, q, 8);
            H2 p; p.u = h0u[r * 8 + gl];
            al0 += (float)p.h[0]; ah0 += (float)p.h[1];
        }
    }
    H2 selfp; selfp.u = h0u[v * 8 + gl];
    float d = dinv[v];
    float h_lo = fmaxf(d * (al0 + al1 + (float)selfp.h[0]) + b1[k], 0.0f);
    float h_hi = fmaxf(d * (ah0 + ah1 + (float)selfp.h[1]) + b1[k + 1], 0.0f);
    float o0 = 0.0f, o1 = 0.0f;
#pragma unroll
    for (int j = 0; j < 8; ++j) {
        float hl = __shfl(h_lo, j, 8);
        float hh = __shfl(h_hi, j, 8);
        o0 += hl * sW[(2 * j) * 16 + k]     + hh * sW[(2 * j + 1) * 16 + k];
        o1 += hl * sW[(2 * j) * 16 + k + 1] + hh * sW[(2 * j + 1) * 16 + k + 1];
    }
    H2 outp;
    outp.h[0] = (_Float16)(d * o0);
    outp.h[1] = (_Float16)(d * o1);
    __builtin_nontemporal_store(outp.u, h1u + v * 8 + gl);
}

// Layer-2 gather (same 8-lane structure) + bias + pool with wave pre-reduction.
__global__ void k_gather2(const int* __restrict__ ptrS, const int* __restrict__ csr,
                          const float* __restrict__ dinv, const unsigned int* __restrict__ h1u,
                          const float* __restrict__ b2, const int* __restrict__ batch,
                          float* __restrict__ g, int N) {
    int t = blockIdx.x * blockDim.x + threadIdx.x;
    int v = t >> 3, gl = t & 7, k = gl * 2;
    bool valid = (v < N);
    float val0 = 0.0f, val1 = 0.0f;
    int bg = 0;
    if (valid) {
        int s = ptrS[v], e = ptrS[v + 1];
        float al0 = 0.0f, ah0 = 0.0f, al1 = 0.0f, ah1 = 0.0f;
        int i = s;
        for (; i + 7 < e; i += 8) {
            int myr = __builtin_nontemporal_load(csr + i + gl);
#pragma unroll
            for (int q = 0; q < 8; ++q) {
                int r = __shfl(myr, q, 8);
                H2 p; p.u = h1u[r * 8 + gl];
                if (q & 1) { al1 += (float)p.h[0]; ah1 += (float)p.h[1]; }
                else       { al0 += (float)p.h[0]; ah0 += (float)p.h[1]; }
            }
        }
        if (i < e) {
            int rem = e - i;
            int myr = (gl < rem) ? __builtin_nontemporal_load(csr + i + gl) : 0;
            for (int q = 0; q < rem; ++q) {
                int r = __shfl(myr, q, 8);
                H2 p; p.u = h1u[r * 8 + gl];
                al0 += (float)p.h[0]; ah0 += (float)p.h[1];
            }
        }
        H2 selfp; selfp.u = h1u[v * 8 + gl];
        float d = dinv[v];
        val0 = d * (al0 + al1 + (float)selfp.h[0]) + b2[k];
        val1 = d * (ah0 + ah1 + (float)selfp.h[1]) + b2[k + 1];
        bg = batch[v];
    }
    int lane = threadIdx.x & 63;
    int bg0 = __shfl(bg, lane & 7, 64);
    bool uni = __all(valid && (bg == bg0));
    if (uni) {
        val0 += __shfl_xor(val0, 8, 64);
        val0 += __shfl_xor(val0, 16, 64);
        val0 += __shfl_xor(val0, 32, 64);
        val1 += __shfl_xor(val1, 8, 64);
        val1 += __shfl_xor(val1, 16, 64);
        val1 += __shfl_xor(val1, 32, 64);
        if (lane < 8) {
            atomicAdd(&g[bg * 16 + k], val0);
            atomicAdd(&g[bg * 16 + k + 1], val1);
        }
    } else if (valid) {
        atomicAdd(&g[bg * 16 + k], val0);
        atomicAdd(&g[bg * 16 + k + 1], val1);
    }
}

// logits = g @ Wl + bl (16x7), then log_softmax over 7. One thread per graph.
__global__ void k_head(const float* __restrict__ g, const float* __restrict__ Wl,
                       const float* __restrict__ bl, float* __restrict__ out, int G) {
    int gi = blockIdx.x * blockDim.x + threadIdx.x;
    if (gi >= G) return;
    float gv[16];
#pragma unroll
    for (int k = 0; k < 16; ++k) gv[k] = g[gi * 16 + k];
    float lo[7];
    float mx = -1e30f;
#pragma unroll
    for (int j = 0; j < 7; ++j) {
        float a = bl[j];
#pragma unroll
        for (int k = 0; k < 16; ++k) a += gv[k] * Wl[k * 7 + j];
        lo[j] = a;
        mx = fmaxf(mx, a);
    }
    float s = 0.0f;
#pragma unroll
    for (int j = 0; j < 7; ++j) s += expf(lo[j] - mx);
    float lse = mx + logf(s);
#pragma unroll
    for (int j = 0; j < 7; ++j) out[gi * 7 + j] = lo[j] - lse;
}

extern "C" void kernel_launch(void* const* d_in, const int* in_sizes, int n_in,
                              void* d_out, int out_size, void* d_ws, size_t ws_size,
                              hipStream_t stream) {
    const float* x    = (const float*)d_in[0];
    const int*   ei   = (const int*)d_in[1];   // [2, E]: row = ei[0:E), col = ei[E:2E)
    const int*   batch = (const int*)d_in[3];
    const float* W1 = (const float*)d_in[4];
    const float* b1 = (const float*)d_in[5];
    const float* W2 = (const float*)d_in[6];
    const float* b2 = (const float*)d_in[7];
    const float* Wl = (const float*)d_in[8];
    const float* bl = (const float*)d_in[9];
    float* out = (float*)d_out;

    const int N = in_sizes[0] / 3;
    const int E = in_sizes[1] / 2;
    const int G = out_size / 7;

    const int* row = ei;
    const int* col = ei + E;

    const int NBLK = (E + CHUNK - 1) / CHUNK;   // must be <= MAXCELL
    const int nb   = (N + BNODES - 1) >> BSH;   // must be <= 511

    int* w = (int*)d_ws;
    float* dinv = (float*)w;            w += N;
    int*   ptrS = w;                    w += N + 1;
    int*   base = w;                    w += nb + 1;
    unsigned short* off = (unsigned short*)w;
    w += ((nb + 1) * NBLK + 1) / 2;     // ushort table, rounded up to int units
    int*   csr  = w;                    w += E;
    int*   temp = w;                    w += E;
    unsigned int* h0u = (unsigned int*)w;  w += 8 * N;
    unsigned int* h1u = (unsigned int*)w;  w += 8 * N;
    float* g    = (float*)w;            w += 16 * G;

    const int TB = 256;
    const int n8  = N * 8;
    const int G16 = G * 16;

    k_bin<<<NBLK, 1024, 0, stream>>>(row, col, temp, off, E, NBLK, nb);
    k_base<<<1, 512, 0, stream>>>(off, base, ptrS, g, E, nb, NBLK, N, G16);
    k_build<<<nb, 1024, 0, stream>>>(temp, off, base, ptrS, dinv, csr, x, W1, h0u, NBLK, N);
    k_gather1<<<(n8 + TB - 1) / TB, TB, 0, stream>>>(ptrS, csr, dinv, h0u, W2, b1, h1u, N);
    k_gather2<<<(n8 + TB - 1) / TB, TB, 0, stream>>>(ptrS, csr, dinv, h1u, b2, batch, g, N);
    k_head<<<(G + TB - 1) / TB, TB, 0, stream>>>(g, Wl, bl, out, G);
}

// Round 11
// 193.238 us; speedup vs baseline: 1.3680x; 1.3680x over previous
//
#include <hip/hip_runtime.h>
#include <math.h>

#define CHUNK 8192
#define BSH 8            // bucket shift: 256 nodes per bucket
#define BNODES 256
#define RAWCAP 9216      // LDS edge capacity per bucket (avg 8192, sigma ~90 -> +11 sigma)
#define MAXCELL 512      // max chunks supported (E <= 4.19M); also requires nb <= 511

// Workspace layout (4-byte units, NO aliasing; ~33 MB total):
//   dinv  : N            rsqrt(1+deg)
//   ptrS  : N+1          CSR row starts (ptrS[N] = E)
//   base  : nb+1         exclusive bucket bases (base[nb] = E)
//   off   : (nb+1)*NBLK  ushort per-(bucket,chunk) exclusive offsets
//   csr   : E            source nodes grouped by destination
//   temp  : E            binned packed edges
//   h0u   : 8N u32       packed fp16 feature table, layer-1 input (dinv-premultiplied)
//   h1u   : 8N u32       packed fp16 feature table, layer-2 input
//   g     : 16G          pooled graph accumulator

union H2 { unsigned int u; _Float16 h[2]; };

// Phase 1: bin this block's 8192-edge chunk by destination bucket.
// 1024 threads, wave-shuffle scan (2 barriers), no global atomics.
__global__ __launch_bounds__(1024) void k_bin(
                      const int* __restrict__ row, const int* __restrict__ col,
                      int* __restrict__ temp, unsigned short* __restrict__ off,
                      int E, int NBLK, int nb) {
    __shared__ int cnt[512];
    __shared__ int cur[512];
    __shared__ int wsum[8];
    __shared__ int stage[CHUNK];
    int blk = blockIdx.x;
    int start = blk * CHUNK;
    int cs = E - start; if (cs > CHUNK) cs = CHUNK;
    int t = threadIdx.x;     // 1024 threads = 16 waves
    int wid = t >> 6, lane = t & 63;
    if (t < 512) cnt[t] = 0;
    __syncthreads();
    for (int i = t; i < cs; i += 1024) atomicAdd(&cnt[col[start + i] >> BSH], 1);
    __syncthreads();
    if (t < 512) {           // waves 0..7 scan the 512 bucket counters
        int c = cnt[t];
        int incl = c;
        for (int o = 1; o < 64; o <<= 1) {
            int u = __shfl_up(incl, o, 64);
            if (lane >= o) incl += u;
        }
        if (lane == 63) wsum[wid] = incl;
        cnt[t] = incl - c;   // within-wave exclusive
    }
    __syncthreads();
    if (t < 512) {
        int wb = 0;
        for (int i = 0; i < wid; ++i) wb += wsum[i];
        int excl = cnt[t] + wb;
        if (t < nb) off[t * NBLK + blk] = (unsigned short)excl;
        if (t == 0) off[nb * NBLK + blk] = (unsigned short)cs;
        cur[t] = excl;
    }
    __syncthreads();
    for (int i = t; i < cs; i += 1024) {
        int cc = col[start + i];         // L2-hot re-read (same 32KB window)
        int rr = row[start + i];
        int p = atomicAdd(&cur[cc >> BSH], 1);
        stage[p] = (rr << BSH) | (cc & (BNODES - 1));
    }
    __syncthreads();
    for (int i = t; i < cs; i += 1024) temp[start + i] = stage[i];
}

// base[t] = row-sum of off row t (sum over chunks of per-chunk exclusive prefixes
// = global exclusive prefix -- no scan needed). One WAVE per row, coalesced
// strided reads + shuffle reduce. Row nb sums chunk sizes = E -> ptrS[N].
// Also zeroes g grid-stride. 392 waves over 98 blocks: ~3 us.
__global__ __launch_bounds__(256) void k_base2(
                       const unsigned short* __restrict__ off, int* __restrict__ base,
                       int* __restrict__ ptrS, float* __restrict__ g,
                       int NBLK, int nbp1, int N, int G16) {
    int gw = (blockIdx.x * 256 + threadIdx.x) >> 6;   // global wave id = row
    int lane = threadIdx.x & 63;
    if (gw < nbp1) {
        const unsigned short* orow = off + (size_t)gw * NBLK;
        int s = 0;
        for (int ch = lane; ch < NBLK; ch += 64) s += orow[ch];
        for (int o = 32; o > 0; o >>= 1) s += __shfl_down(s, o, 64);
        if (lane == 0) {
            base[gw] = s;
            if (gw == nbp1 - 1) ptrS[N] = s;   // = E
        }
    }
    int tid = blockIdx.x * 256 + threadIdx.x;
    for (int i = tid; i < G16; i += gridDim.x * 256) g[i] = 0.0f;
}

// Phase 2: one block per 256-node bucket, 1024 threads. Builds ptrS/dinv/csr
// (LDS-staged, coalesced writeback) AND computes the bucket's h0u rows
// (fused xw1: h0u = fp16(dinv * x@W1), packed pairs). h0u must NOT alias temp.
__global__ __launch_bounds__(1024) void k_build(
                        const int* __restrict__ temp, const unsigned short* __restrict__ off,
                        const int* __restrict__ base, int* __restrict__ ptrS,
                        float* __restrict__ dinv, int* __restrict__ csr,
                        const float* __restrict__ x, const float* __restrict__ W1,
                        unsigned int* __restrict__ h0u, int NBLK, int N) {
    __shared__ int cnt[BNODES];
    __shared__ int cur[BNODES];
    __shared__ int cellstart[MAXCELL];
    __shared__ int soff[MAXCELL];
    __shared__ int wsum[16];
    __shared__ float sdinv[BNODES];
    __shared__ int raw[RAWCAP];
    __shared__ int stage[RAWCAP];
    int b = blockIdx.x;
    int t = threadIdx.x;     // 1024 threads = 16 waves
    int wid = t >> 6, lane = t & 63;
    if (t < BNODES) cnt[t] = 0;
    int len0 = 0;
    if (t < MAXCELL) {
        int s0v = 0;
        if (t < NBLK) {
            s0v = (int)off[b * NBLK + t];
            len0 = (int)off[(b + 1) * NBLK + t] - s0v;
        }
        soff[t] = s0v;
        int v = len0;
        for (int o = 1; o < 64; o <<= 1) {
            int u = __shfl_up(v, o, 64);
            if (lane >= o) v += u;
        }
        if (lane == 63) wsum[wid] = v;
        cellstart[t] = v - len0;
    }
    __syncthreads();
    if (t < MAXCELL) {
        int wb = 0;
        for (int i = 0; i < wid; ++i) wb += wsum[i];
        cellstart[t] += wb;
    }
    __syncthreads();
    int bb = base[b];
    int total = base[b + 1] - bb;
    int grp = t >> 4, gl = t & 15;     // 64 groups of 16 lanes
    for (int cell = grp; cell < NBLK; cell += 64) {
        int s0 = soff[cell];
        int rb = cellstart[cell];
        int len = ((cell + 1 < NBLK) ? cellstart[cell + 1] : total) - rb;
        const int* src = temp + cell * CHUNK + s0;
        for (int j = gl; j < len; j += 16) {
            int e = src[j];
            atomicAdd(&cnt[e & (BNODES - 1)], 1);
            int idx = rb + j;
            if (idx < RAWCAP) raw[idx] = e;
        }
    }
    __syncthreads();
    int c = 0, sincl = 0;
    if (t < BNODES) {
        c = cnt[t];
        sincl = c;
        for (int o = 1; o < 64; o <<= 1) {
            int u = __shfl_up(sincl, o, 64);
            if (lane >= o) sincl += u;
        }
        if (lane == 63) wsum[wid] = sincl;
    }
    __syncthreads();
    if (t < BNODES) {
        int wb2 = 0;
        for (int i = 0; i < wid; ++i) wb2 += wsum[i];
        int lstart = sincl - c + wb2;
        int node = (b << BSH) + t;
        float dv = rsqrtf(1.0f + (float)c);
        sdinv[t] = dv;
        if (node < N) {
            ptrS[node] = bb + lstart;
            dinv[node] = dv;
        }
        cur[t] = lstart;
    }
    __syncthreads();
    int cap = total > RAWCAP ? RAWCAP : total;
    for (int i = t; i < cap; i += 1024) {
        int e = raw[i];
        int p = atomicAdd(&cur[e & (BNODES - 1)], 1);
        int r = e >> BSH;
        if (p < RAWCAP) stage[p] = r;
        else            csr[bb + p] = r;   // statistically unreachable
    }
    if (total > RAWCAP) {                  // statistically unreachable spill
        for (int cell = grp; cell < NBLK; cell += 64) {
            int s0 = soff[cell];
            int rb = cellstart[cell];
            int len = ((cell + 1 < NBLK) ? cellstart[cell + 1] : total) - rb;
            const int* src = temp + cell * CHUNK + s0;
            for (int j = gl; j < len; j += 16) {
                if (rb + j >= RAWCAP) {
                    int e = src[j];
                    int p = atomicAdd(&cur[e & (BNODES - 1)], 1);
                    int r = e >> BSH;
                    if (p < RAWCAP) stage[p] = r;
                    else            csr[bb + p] = r;
                }
            }
        }
    }
    __syncthreads();
    for (int i = t; i < cap; i += 1024) csr[bb + i] = stage[i];
    // Fused xw1 epilogue for this bucket's 256 nodes (2048 packed u32 writes).
    for (int i = t; i < BNODES * 8; i += 1024) {
        int vl = i >> 3, k2 = i & 7, k = k2 * 2;
        int v = (b << BSH) + vl;
        if (v < N) {
            float x0 = x[v * 3 + 0], x1 = x[v * 3 + 1], x2 = x[v * 3 + 2];
            float d = sdinv[vl];
            H2 p;
            p.h[0] = (_Float16)(d * (x0 * W1[k]     + x1 * W1[16 + k]     + x2 * W1[32 + k]));
            p.h[1] = (_Float16)(d * (x0 * W1[k + 1] + x1 * W1[16 + k + 1] + x2 * W1[32 + k + 1]));
            h0u[v * 8 + k2] = p.u;
        }
    }
}

// Layer-1 gather: 8 lanes/node, packed-u32 rows. Per 8-edge window: ONE coalesced
// csr load + __shfl broadcast + 8 u32 table loads servicing 8 nodes/wave.
// f32 accumulation; relu + W2 via 8-lane shfl; packed fp16 store.
__global__ void k_gather1(const int* __restrict__ ptrS, const int* __restrict__ csr,
                          const float* __restrict__ dinv, const unsigned int* __restrict__ h0u,
                          const float* __restrict__ W2, const float* __restrict__ b1,
                          unsigned int* __restrict__ h1u, int N) {
    __shared__ float sW[256];
    sW[threadIdx.x] = W2[threadIdx.x];
    __syncthreads();
    int t = blockIdx.x * blockDim.x + threadIdx.x;
    int v = t >> 3, gl = t & 7, k = gl * 2;
    if (v >= N) return;
    int s = ptrS[v], e = ptrS[v + 1];
    float al0 = 0.0f, ah0 = 0.0f, al1 = 0.0f, ah1 = 0.0f;
    int i = s;
    for (; i + 7 < e; i += 8) {
        int myr = __builtin_nontemporal_load(csr + i + gl);
#pragma unroll
        for (int q = 0; q < 8; ++q) {
            int r = __shfl(myr, q, 8);
            H2 p; p.u = h0u[r * 8 + gl];
            if (q & 1) { al1 += (float)p.h[0]; ah1 += (float)p.h[1]; }
            else       { al0 += (float)p.h[0]; ah0 += (float)p.h[1]; }
        }
    }
    if (i < e) {
        int rem = e - i;
        int myr = (gl < rem) ? __builtin_nontemporal_load(csr + i + gl) : 0;
        for (int q = 0; q < rem; ++q) {
            int r = __shfl(myr, q, 8);
            H2 p; p.u = h0u[r * 8 + gl];
            al0 += (float)p.h[0]; ah0 += (float)p.h[1];
        }
    }
    H2 selfp; selfp.u = h0u[v * 8 + gl];
    float d = dinv[v];
    float h_lo = fmaxf(d * (al0 + al1 + (float)selfp.h[0]) + b1[k], 0.0f);
    float h_hi = fmaxf(d * (ah0 + ah1 + (float)selfp.h[1]) + b1[k + 1], 0.0f);
    float o0 = 0.0f, o1 = 0.0f;
#pragma unroll
    for (int j = 0; j < 8; ++j) {
        float hl = __shfl(h_lo, j, 8);
        float hh = __shfl(h_hi, j, 8);
        o0 += hl * sW[(2 * j) * 16 + k]     + hh * sW[(2 * j + 1) * 16 + k];
        o1 += hl * sW[(2 * j) * 16 + k + 1] + hh * sW[(2 * j + 1) * 16 + k + 1];
    }
    H2 outp;
    outp.h[0] = (_Float16)(d * o0);
    outp.h[1] = (_Float16)(d * o1);
    __builtin_nontemporal_store(outp.u, h1u + v * 8 + gl);
}

// Layer-2 gather (same 8-lane structure) + bias + pool with wave pre-reduction.
__global__ void k_gather2(const int* __restrict__ ptrS, const int* __restrict__ csr,
                          const float* __restrict__ dinv, const unsigned int* __restrict__ h1u,
                          const float* __restrict__ b2, const int* __restrict__ batch,
                          float* __restrict__ g, int N) {
    int t = blockIdx.x * blockDim.x + threadIdx.x;
    int v = t >> 3, gl = t & 7, k = gl * 2;
    bool valid = (v < N);
    float val0 = 0.0f, val1 = 0.0f;
    int bg = 0;
    if (valid) {
        int s = ptrS[v], e = ptrS[v + 1];
        float al0 = 0.0f, ah0 = 0.0f, al1 = 0.0f, ah1 = 0.0f;
        int i = s;
        for (; i + 7 < e; i += 8) {
            int myr = __builtin_nontemporal_load(csr + i + gl);
#pragma unroll
            for (int q = 0; q < 8; ++q) {
                int r = __shfl(myr, q, 8);
                H2 p; p.u = h1u[r * 8 + gl];
                if (q & 1) { al1 += (float)p.h[0]; ah1 += (float)p.h[1]; }
                else       { al0 += (float)p.h[0]; ah0 += (float)p.h[1]; }
            }
        }
        if (i < e) {
            int rem = e - i;
            int myr = (gl < rem) ? __builtin_nontemporal_load(csr + i + gl) : 0;
            for (int q = 0; q < rem; ++q) {
                int r = __shfl(myr, q, 8);
                H2 p; p.u = h1u[r * 8 + gl];
                al0 += (float)p.h[0]; ah0 += (float)p.h[1];
            }
        }
        H2 selfp; selfp.u = h1u[v * 8 + gl];
        float d = dinv[v];
        val0 = d * (al0 + al1 + (float)selfp.h[0]) + b2[k];
        val1 = d * (ah0 + ah1 + (float)selfp.h[1]) + b2[k + 1];
        bg = batch[v];
    }
    int lane = threadIdx.x & 63;
    int bg0 = __shfl(bg, lane & 7, 64);
    bool uni = __all(valid && (bg == bg0));
    if (uni) {
        val0 += __shfl_xor(val0, 8, 64);
        val0 += __shfl_xor(val0, 16, 64);
        val0 += __shfl_xor(val0, 32, 64);
        val1 += __shfl_xor(val1, 8, 64);
        val1 += __shfl_xor(val1, 16, 64);
        val1 += __shfl_xor(val1, 32, 64);
        if (lane < 8) {
            atomicAdd(&g[bg * 16 + k], val0);
            atomicAdd(&g[bg * 16 + k + 1], val1);
        }
    } else if (valid) {
        atomicAdd(&g[bg * 16 + k], val0);
        atomicAdd(&g[bg * 16 + k + 1], val1);
    }
}

// logits = g @ Wl + bl (16x7), then log_softmax over 7. One thread per graph.
__global__ void k_head(const float* __restrict__ g, const float* __restrict__ Wl,
                       const float* __restrict__ bl, float* __restrict__ out, int G) {
    int gi = blockIdx.x * blockDim.x + threadIdx.x;
    if (gi >= G) return;
    float gv[16];
#pragma unroll
    for (int k = 0; k < 16; ++k) gv[k] = g[gi * 16 + k];
    float lo[7];
    float mx = -1e30f;
#pragma unroll
    for (int j = 0; j < 7; ++j) {
        float a = bl[j];
#pragma unroll
        for (int k = 0; k < 16; ++k) a += gv[k] * Wl[k * 7 + j];
        lo[j] = a;
        mx = fmaxf(mx, a);
    }
    float s = 0.0f;
#pragma unroll
    for (int j = 0; j < 7; ++j) s += expf(lo[j] - mx);
    float lse = mx + logf(s);
#pragma unroll
    for (int j = 0; j < 7; ++j) out[gi * 7 + j] = lo[j] - lse;
}

extern "C" void kernel_launch(void* const* d_in, const int* in_sizes, int n_in,
                              void* d_out, int out_size, void* d_ws, size_t ws_size,
                              hipStream_t stream) {
    const float* x    = (const float*)d_in[0];
    const int*   ei   = (const int*)d_in[1];   // [2, E]: row = ei[0:E), col = ei[E:2E)
    const int*   batch = (const int*)d_in[3];
    const float* W1 = (const float*)d_in[4];
    const float* b1 = (const float*)d_in[5];
    const float* W2 = (const float*)d_in[6];
    const float* b2 = (const float*)d_in[7];
    const float* Wl = (const float*)d_in[8];
    const float* bl = (const float*)d_in[9];
    float* out = (float*)d_out;

    const int N = in_sizes[0] / 3;
    const int E = in_sizes[1] / 2;
    const int G = out_size / 7;

    const int* row = ei;
    const int* col = ei + E;

    const int NBLK = (E + CHUNK - 1) / CHUNK;   // must be <= MAXCELL
    const int nb   = (N + BNODES - 1) >> BSH;   // must be <= 511

    int* w = (int*)d_ws;
    float* dinv = (float*)w;            w += N;
    int*   ptrS = w;                    w += N + 1;
    int*   base = w;                    w += nb + 1;
    unsigned short* off = (unsigned short*)w;
    w += ((nb + 1) * NBLK + 1) / 2;     // ushort table, rounded up to int units
    int*   csr  = w;                    w += E;
    int*   temp = w;                    w += E;
    unsigned int* h0u = (unsigned int*)w;  w += 8 * N;
    unsigned int* h1u = (unsigned int*)w;  w += 8 * N;
    float* g    = (float*)w;            w += 16 * G;

    const int TB = 256;
    const int n8  = N * 8;
    const int G16 = G * 16;
    const int nbp1 = nb + 1;
    const int baseBlocks = (nbp1 * 64 + 255) / 256;

    k_bin<<<NBLK, 1024, 0, stream>>>(row, col, temp, off, E, NBLK, nb);
    k_base2<<<baseBlocks, 256, 0, stream>>>(off, base, ptrS, g, NBLK, nbp1, N, G16);
    k_build<<<nb, 1024, 0, stream>>>(temp, off, base, ptrS, dinv, csr, x, W1, h0u, NBLK, N);
    k_gather1<<<(n8 + TB - 1) / TB, TB, 0, stream>>>(ptrS, csr, dinv, h0u, W2, b1, h1u, N);
    k_gather2<<<(n8 + TB - 1) / TB, TB, 0, stream>>>(ptrS, csr, dinv, h1u, b2, batch, g, N);
    k_head<<<(G + TB - 1) / TB, TB, 0, stream>>>(g, Wl, bl, out, G);
}